// Round 8
// baseline (510.531 us; speedup 1.0000x reference)
//
#include <hip/hip_runtime.h>

typedef __attribute__((ext_vector_type(8))) short short8v;
typedef __attribute__((ext_vector_type(8))) unsigned short ushort8v;
typedef __attribute__((ext_vector_type(4))) unsigned short ushort4v;
typedef __attribute__((ext_vector_type(4))) float f32x4;

__device__ __forceinline__ unsigned short f2b(float f) {
  unsigned int u = __float_as_uint(f);
  unsigned int r = (u + 0x7FFFu + ((u >> 16) & 1u)) >> 16;
  return (unsigned short)r;
}
__device__ __forceinline__ float b2f(unsigned short h) {
  return __uint_as_float(((unsigned int)h) << 16);
}
__device__ __forceinline__ float gelu_f(float x) {
  float z = 0.7978845608028654f * (x + 0.044715f * x * x * x);
  float e = __expf(2.0f * z);
  float t = 1.0f - 2.0f / (e + 1.0f);
  return 0.5f * x * (1.0f + t);
}
__device__ __forceinline__ void gload16(const void* g, void* l) {
  __builtin_amdgcn_global_load_lds((const __attribute__((address_space(1))) unsigned int*)g,
                                   (__attribute__((address_space(3))) unsigned int*)l,
                                   16, 0, 0);
}
// bijective XCD swizzle (m204)
__device__ __forceinline__ int xcd_swz(int wgid, int nwg) {
  int q = nwg >> 3, r = nwg & 7;
  int xcd = wgid & 7, idx = wgid >> 3;
  return (xcd < r ? xcd * (q + 1) : r * (q + 1) + (xcd - r) * q) + idx;
}

// ---------------- merged weight prep: 8 transposes (f32 [K][N] -> bf16 [N][K]) + enc cvt ----
__global__ __launch_bounds__(256) void k_wprep(
    const float* aw, unsigned short* awt,
    const float* apw, unsigned short* apwt,
    const float* cw, unsigned short* cwt,
    const float* cpw, unsigned short* cpwt,
    const float* fw, unsigned short* fwt,
    const float* mw, unsigned short* mwt,
    const float* dw, unsigned short* dwt,
    const float* uw, unsigned short* uwt,
    const float* enc, unsigned short* encb) {
  __shared__ float tile[64][65];
  int bid = blockIdx.x, t = threadIdx.x;
  const float* w; unsigned short* wt; int K, N, gx, l;
  if      (bid < 768)  { w = aw;  wt = awt;  K = 1024; N = 3072; gx = 48; l = bid; }
  else if (bid < 1024) { w = apw; wt = apwt; K = 1024; N = 1024; gx = 16; l = bid - 768; }
  else if (bid < 1792) { w = cw;  wt = cwt;  K = 1024; N = 3072; gx = 48; l = bid - 1024; }
  else if (bid < 2048) { w = cpw; wt = cpwt; K = 1024; N = 1024; gx = 16; l = bid - 1792; }
  else if (bid < 3072) { w = fw;  wt = fwt;  K = 1024; N = 4096; gx = 64; l = bid - 2048; }
  else if (bid < 4096) { w = mw;  wt = mwt;  K = 4096; N = 1024; gx = 16; l = bid - 3072; }
  else if (bid < 4160) { w = dw;  wt = dwt;  K = 1024; N = 256;  gx = 4;  l = bid - 4096; }
  else if (bid < 4224) { w = uw;  wt = uwt;  K = 256;  N = 1024; gx = 16; l = bid - 4160; }
  else {
    size_t i = ((size_t)(bid - 4224) * 256 + t) * 4;
    f32x4 v = *(const f32x4*)&enc[i];
    ushort4v o;
#pragma unroll
    for (int j = 0; j < 4; ++j) o[j] = f2b(v[j]);
    *(ushort4v*)&encb[i] = o;
    return;
  }
  int bx = l % gx, by = l / gx;
  int tn = bx * 64, tk = by * 64;
  int c = t & 63, r0 = t >> 6;
#pragma unroll
  for (int p = 0; p < 16; ++p) {
    int r = r0 + p * 4;
    tile[r][c] = w[(size_t)(tk + r) * N + tn + c];
  }
  __syncthreads();
#pragma unroll
  for (int p = 0; p < 16; ++p) {
    int r = r0 + p * 4;
    wt[(size_t)(tn + r) * K + tk + c] = f2b(tile[c][r]);
  }
}

// ---------------- LayerNorm over C=1024, out bf16 ----------------
__global__ __launch_bounds__(256) void k_ln(const float* __restrict__ in,
                                            const float* __restrict__ g,
                                            const float* __restrict__ b,
                                            unsigned short* __restrict__ out) {
  int row = blockIdx.x;
  const float* x = in + (size_t)row * 1024;
  int t = threadIdx.x;
  float v0 = x[t], v1 = x[t + 256], v2 = x[t + 512], v3 = x[t + 768];
  float s = v0 + v1 + v2 + v3;
  float s2 = v0 * v0 + v1 * v1 + v2 * v2 + v3 * v3;
#pragma unroll
  for (int m = 1; m < 64; m <<= 1) { s += __shfl_xor(s, m); s2 += __shfl_xor(s2, m); }
  __shared__ float rs[4], rs2[4];
  int w = t >> 6;
  if ((t & 63) == 0) { rs[w] = s; rs2[w] = s2; }
  __syncthreads();
  s = rs[0] + rs[1] + rs[2] + rs[3];
  s2 = rs2[0] + rs2[1] + rs2[2] + rs2[3];
  float mean = s * (1.0f / 1024.0f);
  float var = s2 * (1.0f / 1024.0f) - mean * mean;
  float rinv = rsqrtf(var + 1e-5f);
  unsigned short* o = out + (size_t)row * 1024;
  o[t]       = f2b((v0 - mean) * rinv * g[t]       + b[t]);
  o[t + 256] = f2b((v1 - mean) * rinv * g[t + 256] + b[t + 256]);
  o[t + 512] = f2b((v2 - mean) * rinv * g[t + 512] + b[t + 512]);
  o[t + 768] = f2b((v3 - mean) * rinv * g[t + 768] + b[t + 768]);
}

// ---------------- m97-structure GEMM: 128x128, BK=32, SINGLE-buffered 16KB LDS ----------------
// 4 blocks/CU co-resident; inter-block overlap hides the per-step barrier drain (m114).
// LDS: A[128][32] at u16 0..8192, B[128][32] at 8192..16384.
// chunk-swizzle: row r slot s holds global chunk s^((r>>1)&3) (src-preswizzled, 0 conflicts).
template <bool GELU, bool WF32, bool WBF16, int NRES, bool RES1B>
__global__ __launch_bounds__(256) void k_gemm(
    const unsigned short* __restrict__ A, int lda,
    const unsigned short* __restrict__ W, int ldw,
    const float* __restrict__ bias,
    const float* __restrict__ res1, const unsigned short* __restrict__ res1b,
    const float* __restrict__ res2,
    float* __restrict__ outF, unsigned short* __restrict__ outB,
    int M, int N, int K, int nbx) {
  __shared__ unsigned short lds[16384];
  const int t = threadIdx.x;
  const int swz = xcd_swz(blockIdx.x, gridDim.x);
  const int tileM = (swz / nbx) * 128, tileN = (swz % nbx) * 128;
  const int lane = t & 63, w = t >> 6;
  const int wm = (w >> 1) * 64, wn = (w & 1) * 64;
  const int lr16 = lane & 15, kc4 = lane >> 4;

  const int row1 = t >> 2, row2 = (t >> 2) + 64, cs = t & 3;
  const int c1 = (cs ^ ((row1 >> 1) & 3)) * 8;
  const int c2 = (cs ^ ((row2 >> 1) & 3)) * 8;
  int gr1 = tileM + row1; if (gr1 >= M) gr1 = M - 1;
  int gr2 = tileM + row2; if (gr2 >= M) gr2 = M - 1;
  const unsigned short* a1 = A + (size_t)gr1 * lda + c1;
  const unsigned short* a2 = A + (size_t)gr2 * lda + c2;
  const unsigned short* w1 = W + (size_t)(tileN + row1) * ldw + c1;
  const unsigned short* w2 = W + (size_t)(tileN + row2) * ldw + c2;

  f32x4 acc[4][4];
#pragma unroll
  for (int i = 0; i < 4; ++i)
#pragma unroll
    for (int j = 0; j < 4; ++j) acc[i][j] = f32x4{0.f, 0.f, 0.f, 0.f};

  const int nsteps = K >> 5;
  for (int ks = 0; ks < nsteps; ++ks) {
    const int koff = ks << 5;
    gload16(a1 + koff, &lds[t * 8]);
    gload16(a2 + koff, &lds[2048 + t * 8]);
    gload16(w1 + koff, &lds[8192 + t * 8]);
    gload16(w2 + koff, &lds[10240 + t * 8]);
    __syncthreads();
    short8v af[4], bfr[4];
#pragma unroll
    for (int i = 0; i < 4; ++i) {
      int r = wm + i * 16 + lr16;
      af[i] = *(const short8v*)&lds[r * 32 + (kc4 ^ ((r >> 1) & 3)) * 8];
    }
#pragma unroll
    for (int j = 0; j < 4; ++j) {
      int r = wn + j * 16 + lr16;
      bfr[j] = *(const short8v*)&lds[8192 + r * 32 + (kc4 ^ ((r >> 1) & 3)) * 8];
    }
#pragma unroll
    for (int i = 0; i < 4; ++i)
#pragma unroll
      for (int j = 0; j < 4; ++j)
        acc[i][j] = __builtin_amdgcn_mfma_f32_16x16x32_bf16(af[i], bfr[j], acc[i][j], 0, 0, 0);
    __syncthreads();
  }

#pragma unroll
  for (int mi = 0; mi < 4; ++mi) {
#pragma unroll
    for (int n = 0; n < 4; ++n) {
      int col = tileN + wn + n * 16 + lr16;
      float bv = bias[col];
#pragma unroll
      for (int qi = 0; qi < 4; ++qi) {
        int row = tileM + wm + mi * 16 + kc4 * 4 + qi;
        if (row < M) {
          float v = acc[mi][n][qi] + bv;
          if (GELU) v = gelu_f(v);
          size_t o = (size_t)row * N + col;
          if (NRES >= 1) v += RES1B ? b2f(res1b[o]) : res1[o];
          if (NRES >= 2) v += res2[o];
          if (WF32) outF[o] = v;
          if (WBF16) outB[o] = f2b(v);
        }
      }
    }
  }
}

// ---------------- V transpose: src[b*TB+tok][src_off+h*64+d] -> dst[bh][d][tok] ----------------
__global__ __launch_bounds__(256) void k_vtrans(const unsigned short* __restrict__ src,
                                                int src_stride, int src_off, int TB,
                                                unsigned short* __restrict__ dst, int dst_tstride) {
  __shared__ unsigned short tile[64][72];
  int tb = blockIdx.x, bh = blockIdx.y;
  int b = bh >> 4, h = bh & 15;
  int t = threadIdx.x;
  int r = t >> 2, c0 = (t & 3) * 16;
  int tok = tb * 64 + r; if (tok >= TB) tok = TB - 1;
  const unsigned short* s = src + (size_t)(b * TB + tok) * src_stride + src_off + h * 64 + c0;
  *(ushort8v*)&tile[r][c0] = *(const ushort8v*)s;
  *(ushort8v*)&tile[r][c0 + 8] = *(const ushort8v*)(s + 8);
  __syncthreads();
  unsigned short tmp[16];
#pragma unroll
  for (int j = 0; j < 16; ++j) tmp[j] = tile[c0 + j][r];
  unsigned short* dp = dst + ((size_t)bh * 64 + r) * dst_tstride + tb * 64 + c0;
  *(ushort8v*)dp = *(const ushort8v*)&tmp[0];
  *(ushort8v*)(dp + 8) = *(const ushort8v*)&tmp[8];
}

// ---------------- MFMA flash attention ----------------
template <bool CAUSAL>
__global__ __launch_bounds__(256) void k_attn(
    const unsigned short* __restrict__ Qb, int q_stride,
    const unsigned short* __restrict__ Kb, int k_stride, int k_off, int TKR,
    const unsigned short* __restrict__ Vt, int vt_tstride,
    unsigned short* __restrict__ out, int Tk) {
  __shared__ unsigned short Kl[64 * 72];
  __shared__ unsigned short Vl[64 * 72];
  __shared__ unsigned short Pl[4][16 * 72];
  const int swz = xcd_swz(blockIdx.x, gridDim.x);
  int qb = swz & 15, bh = swz >> 4;
  int b = bh >> 4, h = bh & 15;
  int t = threadIdx.x, lane = t & 63, w = t >> 6;
  int g = lane >> 4, lc = lane & 15;

  int qrow_g = qb * 64 + w * 16 + lc;
  const unsigned short* qp = Qb + (size_t)(b * 1024 + qrow_g) * q_stride + h * 64 + g * 8;
  short8v aq0 = *(const short8v*)qp;
  short8v aq1 = *(const short8v*)(qp + 32);

  f32x4 o[4];
  float m_[4], l_[4];
#pragma unroll
  for (int dt = 0; dt < 4; ++dt) o[dt] = f32x4{0.f, 0.f, 0.f, 0.f};
#pragma unroll
  for (int r = 0; r < 4; ++r) { m_[r] = -3.0e38f; l_[r] = 0.0f; }

  int srow = t >> 2;
  int sc = (t & 3) * 16;
  int ntiles = CAUSAL ? (qb + 1) : ((Tk + 63) >> 6);

  for (int kt = 0; kt < ntiles; ++kt) {
    __syncthreads();
    {
      int kg = kt * 64 + srow;
      if (!CAUSAL && kg >= Tk) kg = Tk - 1;
      const unsigned short* ks = Kb + (size_t)(b * TKR + kg) * k_stride + k_off + h * 64 + sc;
      *(ushort8v*)&Kl[srow * 72 + sc]     = *(const ushort8v*)ks;
      *(ushort8v*)&Kl[srow * 72 + sc + 8] = *(const ushort8v*)(ks + 8);
      const unsigned short* vs = Vt + ((size_t)bh * 64 + srow) * vt_tstride + kt * 64 + sc;
      *(ushort8v*)&Vl[srow * 72 + sc]     = *(const ushort8v*)vs;
      *(ushort8v*)&Vl[srow * 72 + sc + 8] = *(const ushort8v*)(vs + 8);
    }
    __syncthreads();

    f32x4 s[4];
#pragma unroll
    for (int jt = 0; jt < 4; ++jt) {
      short8v bk0 = *(const short8v*)&Kl[(jt * 16 + lc) * 72 + g * 8];
      short8v bk1 = *(const short8v*)&Kl[(jt * 16 + lc) * 72 + g * 8 + 32];
      f32x4 acc = f32x4{0.f, 0.f, 0.f, 0.f};
      acc = __builtin_amdgcn_mfma_f32_16x16x32_bf16(aq0, bk0, acc, 0, 0, 0);
      acc = __builtin_amdgcn_mfma_f32_16x16x32_bf16(aq1, bk1, acc, 0, 0, 0);
      s[jt] = acc;
    }
#pragma unroll
    for (int jt = 0; jt < 4; ++jt)
#pragma unroll
      for (int r = 0; r < 4; ++r) {
        float sv = s[jt][r] * 0.125f;
        bool masked = CAUSAL ? (kt == qb && (jt * 16 + lc) > (w * 16 + g * 4 + r))
                             : (kt * 64 + jt * 16 + lc >= Tk);
        s[jt][r] = masked ? -3.0e38f : sv;
      }
    float f[4];
#pragma unroll
    for (int r = 0; r < 4; ++r) {
      float mx = fmaxf(fmaxf(s[0][r], s[1][r]), fmaxf(s[2][r], s[3][r]));
      mx = fmaxf(mx, __shfl_xor(mx, 1));
      mx = fmaxf(mx, __shfl_xor(mx, 2));
      mx = fmaxf(mx, __shfl_xor(mx, 4));
      mx = fmaxf(mx, __shfl_xor(mx, 8));
      float mnew = fmaxf(m_[r], mx);
      f[r] = __expf(m_[r] - mnew);
      m_[r] = mnew;
      float rsum = 0.0f;
#pragma unroll
      for (int jt = 0; jt < 4; ++jt) {
        float p = __expf(s[jt][r] - mnew);
        s[jt][r] = p;
        rsum += p;
      }
      rsum += __shfl_xor(rsum, 1);
      rsum += __shfl_xor(rsum, 2);
      rsum += __shfl_xor(rsum, 4);
      rsum += __shfl_xor(rsum, 8);
      l_[r] = l_[r] * f[r] + rsum;
    }
#pragma unroll
    for (int dt = 0; dt < 4; ++dt)
#pragma unroll
      for (int r = 0; r < 4; ++r) o[dt][r] *= f[r];
#pragma unroll
    for (int jt = 0; jt < 4; ++jt)
#pragma unroll
      for (int r = 0; r < 4; ++r)
        Pl[w][(g * 4 + r) * 72 + jt * 16 + lc] = f2b(s[jt][r]);
    short8v ap0 = *(const short8v*)&Pl[w][lc * 72 + g * 8];
    short8v ap1 = *(const short8v*)&Pl[w][lc * 72 + g * 8 + 32];
#pragma unroll
    for (int dt = 0; dt < 4; ++dt) {
      short8v bv0 = *(const short8v*)&Vl[(dt * 16 + lc) * 72 + g * 8];
      short8v bv1 = *(const short8v*)&Vl[(dt * 16 + lc) * 72 + g * 8 + 32];
      o[dt] = __builtin_amdgcn_mfma_f32_16x16x32_bf16(ap0, bv0, o[dt], 0, 0, 0);
      o[dt] = __builtin_amdgcn_mfma_f32_16x16x32_bf16(ap1, bv1, o[dt], 0, 0, 0);
    }
  }
  size_t orow = (size_t)(b * 1024 + qb * 64 + w * 16) * 1024 + h * 64;
#pragma unroll
  for (int r = 0; r < 4; ++r) {
    float inv = 1.0f / l_[r];
#pragma unroll
    for (int dt = 0; dt < 4; ++dt)
      out[orow + (size_t)(g * 4 + r) * 1024 + dt * 16 + lc] = f2b(o[dt][r] * inv);
  }
}

extern "C" void kernel_launch(void* const* d_in, const int* in_sizes, int n_in,
                              void* d_out, int out_size, void* d_ws, size_t ws_size,
                              hipStream_t stream) {
  (void)in_sizes; (void)n_in; (void)out_size; (void)ws_size;
  const float* x       = (const float*)d_in[0];
  const float* enc     = (const float*)d_in[1];
  const float* ln1_g   = (const float*)d_in[3];
  const float* ln1_b   = (const float*)d_in[4];
  const float* ln2_g   = (const float*)d_in[5];
  const float* ln2_b   = (const float*)d_in[6];
  const float* ln3_g   = (const float*)d_in[7];
  const float* ln3_b   = (const float*)d_in[8];
  const float* attn_w  = (const float*)d_in[9];
  const float* attn_b  = (const float*)d_in[10];
  const float* aproj_w = (const float*)d_in[11];
  const float* aproj_b = (const float*)d_in[12];
  const float* ca_w    = (const float*)d_in[13];
  const float* ca_b    = (const float*)d_in[14];
  const float* caproj_w= (const float*)d_in[15];
  const float* caproj_b= (const float*)d_in[16];
  const float* fc_w    = (const float*)d_in[17];
  const float* fc_b    = (const float*)d_in[18];
  const float* mproj_w = (const float*)d_in[19];
  const float* mproj_b = (const float*)d_in[20];
  const float* down_w  = (const float*)d_in[21];
  const float* down_b  = (const float*)d_in[22];
  const float* up_w    = (const float*)d_in[23];
  const float* up_b    = (const float*)d_in[24];
  float* out = (float*)d_out;
  char* ws = (char*)d_ws;

  const size_t O_WATTN = 0, O_WAPROJ = 6291456, O_WCA = 8388608, O_WCAPROJ = 14680064,
               O_WFC = 16777216, O_WMPROJ = 25165824, O_WDOWN = 33554432, O_WUP = 34078720,
               O_ENC = 34603008, O_LN = 36708352, O_BIG = 45096960,
               O_XRES = 78651392, O_ATTN = 112205824;

  unsigned short* wt_attn   = (unsigned short*)(ws + O_WATTN);
  unsigned short* wt_aproj  = (unsigned short*)(ws + O_WAPROJ);
  unsigned short* wt_ca     = (unsigned short*)(ws + O_WCA);
  unsigned short* wt_caproj = (unsigned short*)(ws + O_WCAPROJ);
  unsigned short* wt_fc     = (unsigned short*)(ws + O_WFC);
  unsigned short* wt_mproj  = (unsigned short*)(ws + O_WMPROJ);
  unsigned short* wt_down   = (unsigned short*)(ws + O_WDOWN);
  unsigned short* wt_up     = (unsigned short*)(ws + O_WUP);
  unsigned short* encbf     = (unsigned short*)(ws + O_ENC);
  unsigned short* lnout     = (unsigned short*)(ws + O_LN);
  unsigned short* hbf       = (unsigned short*)(ws + O_LN);            // after fc consumed
  unsigned short* qkvb      = (unsigned short*)(ws + O_BIG);
  unsigned short* vt_self   = (unsigned short*)(ws + O_BIG + 25165824); // alive with qkvb
  unsigned short* q2b       = (unsigned short*)(ws + O_BIG);           // after self path done
  unsigned short* kvb       = (unsigned short*)(ws + O_BIG + 8388608);
  unsigned short* vt_cross  = (unsigned short*)(ws + O_BIG + 12599296);
  unsigned short* caout     = (unsigned short*)(ws + O_BIG + 15220736);
  unsigned short* fcout     = (unsigned short*)(ws + O_BIG);           // after cross path done
  float*          xres      = (float*)(ws + O_XRES);
  unsigned short* attnout   = (unsigned short*)(ws + O_ATTN);
  unsigned short* dmid      = (unsigned short*)(ws + O_ATTN);          // after aproj consumed

  dim3 blk(256);

  // 1. merged weight prep (8 transposes + enc cvt)
  k_wprep<<<dim3(5252), blk, 0, stream>>>(
      attn_w, wt_attn, aproj_w, wt_aproj, ca_w, wt_ca, caproj_w, wt_caproj,
      fc_w, wt_fc, mproj_w, wt_mproj, down_w, wt_down, up_w, wt_up, enc, encbf);

  // 3. ln1(x) ; qkv ; V-transpose ; self-attn ; aproj + residual(x) -> xres
  k_ln<<<dim3(4096), blk, 0, stream>>>(x, ln1_g, ln1_b, lnout);
  k_gemm<false, false, true, 0, false><<<dim3(768), blk, 0, stream>>>(
      lnout, 1024, wt_attn, 1024, attn_b, nullptr, nullptr, nullptr, nullptr, qkvb,
      4096, 3072, 1024, 24);
  k_vtrans<<<dim3(16, 64), blk, 0, stream>>>(qkvb, 3072, 2048, 1024, vt_self, 1024);
  k_attn<true><<<dim3(1024), blk, 0, stream>>>(
      qkvb, 3072, qkvb, 3072, 1024, 1024, vt_self, 1024, attnout, 1024);
  k_gemm<false, true, false, 1, false><<<dim3(256), blk, 0, stream>>>(
      attnout, 1024, wt_aproj, 1024, aproj_b, x, nullptr, nullptr, xres, nullptr,
      4096, 1024, 1024, 8);

  // 4. ln2(xres) ; q2 ; kv(enc) ; V-transpose ; cross-attn ; caproj + residual -> xres
  k_ln<<<dim3(4096), blk, 0, stream>>>(xres, ln2_g, ln2_b, lnout);
  k_gemm<false, false, true, 0, false><<<dim3(256), blk, 0, stream>>>(
      lnout, 1024, wt_ca, 1024, ca_b, nullptr, nullptr, nullptr, nullptr, q2b,
      4096, 1024, 1024, 8);
  k_gemm<false, false, true, 0, false><<<dim3(144), blk, 0, stream>>>(
      encbf, 1024, wt_ca + (size_t)1024 * 1024, 1024, ca_b + 1024, nullptr, nullptr,
      nullptr, nullptr, kvb, 1028, 2048, 1024, 16);
  k_vtrans<<<dim3(5, 64), blk, 0, stream>>>(kvb, 2048, 1024, 257, vt_cross, 320);
  k_attn<false><<<dim3(1024), blk, 0, stream>>>(
      q2b, 1024, kvb, 2048, 0, 257, vt_cross, 320, caout, 257);
  k_gemm<false, true, false, 1, false><<<dim3(256), blk, 0, stream>>>(
      caout, 1024, wt_caproj, 1024, caproj_b, xres, nullptr, nullptr, xres, nullptr,
      4096, 1024, 1024, 8);

  // 5. ln3(xres) ; fc+gelu ; mproj -> hbf
  k_ln<<<dim3(4096), blk, 0, stream>>>(xres, ln3_g, ln3_b, lnout);
  k_gemm<true, false, true, 0, false><<<dim3(1024), blk, 0, stream>>>(
      lnout, 1024, wt_fc, 1024, fc_b, nullptr, nullptr, nullptr, nullptr, fcout,
      4096, 4096, 1024, 32);
  k_gemm<false, false, true, 0, false><<<dim3(256), blk, 0, stream>>>(
      fcout, 4096, wt_mproj, 4096, mproj_b, nullptr, nullptr, nullptr, nullptr, hbf,
      4096, 1024, 4096, 8);

  // 6. adapter: down+gelu ; up + up_b + h(bf16) + xres -> out
  k_gemm<true, false, true, 0, false><<<dim3(64), blk, 0, stream>>>(
      hbf, 1024, wt_down, 1024, down_b, nullptr, nullptr, nullptr, nullptr, dmid,
      4096, 256, 1024, 2);
  k_gemm<false, true, false, 2, true><<<dim3(256), blk, 0, stream>>>(
      dmid, 256, wt_up, 256, up_b, nullptr, hbf, xres, out, nullptr,
      4096, 1024, 256, 8);
}

// Round 9
// 472.652 us; speedup vs baseline: 1.0801x; 1.0801x over previous
//
#include <hip/hip_runtime.h>

typedef __attribute__((ext_vector_type(8))) short short8v;
typedef __attribute__((ext_vector_type(8))) unsigned short ushort8v;
typedef __attribute__((ext_vector_type(4))) unsigned short ushort4v;
typedef __attribute__((ext_vector_type(4))) float f32x4;

__device__ __forceinline__ unsigned short f2b(float f) {
  unsigned int u = __float_as_uint(f);
  unsigned int r = (u + 0x7FFFu + ((u >> 16) & 1u)) >> 16;
  return (unsigned short)r;
}
__device__ __forceinline__ float b2f(unsigned short h) {
  return __uint_as_float(((unsigned int)h) << 16);
}
__device__ __forceinline__ float gelu_f(float x) {
  float z = 0.7978845608028654f * (x + 0.044715f * x * x * x);
  float e = __expf(2.0f * z);
  float t = 1.0f - 2.0f / (e + 1.0f);
  return 0.5f * x * (1.0f + t);
}
// bijective XCD swizzle (m204)
__device__ __forceinline__ int xcd_swz(int wgid, int nwg) {
  int q = nwg >> 3, r = nwg & 7;
  int xcd = wgid & 7, idx = wgid >> 3;
  return (xcd < r ? xcd * (q + 1) : r * (q + 1) + (xcd - r) * q) + idx;
}

// ---------------- merged weight prep: 8 transposes (f32 [K][N] -> bf16 [N][K]) + enc cvt ----
__global__ __launch_bounds__(256) void k_wprep(
    const float* aw, unsigned short* awt,
    const float* apw, unsigned short* apwt,
    const float* cw, unsigned short* cwt,
    const float* cpw, unsigned short* cpwt,
    const float* fw, unsigned short* fwt,
    const float* mw, unsigned short* mwt,
    const float* dw, unsigned short* dwt,
    const float* uw, unsigned short* uwt,
    const float* enc, unsigned short* encb) {
  __shared__ float tile[64][65];
  int bid = blockIdx.x, t = threadIdx.x;
  const float* w; unsigned short* wt; int K, N, gx, l;
  if      (bid < 768)  { w = aw;  wt = awt;  K = 1024; N = 3072; gx = 48; l = bid; }
  else if (bid < 1024) { w = apw; wt = apwt; K = 1024; N = 1024; gx = 16; l = bid - 768; }
  else if (bid < 1792) { w = cw;  wt = cwt;  K = 1024; N = 3072; gx = 48; l = bid - 1024; }
  else if (bid < 2048) { w = cpw; wt = cpwt; K = 1024; N = 1024; gx = 16; l = bid - 1792; }
  else if (bid < 3072) { w = fw;  wt = fwt;  K = 1024; N = 4096; gx = 64; l = bid - 2048; }
  else if (bid < 4096) { w = mw;  wt = mwt;  K = 4096; N = 1024; gx = 16; l = bid - 3072; }
  else if (bid < 4160) { w = dw;  wt = dwt;  K = 1024; N = 256;  gx = 4;  l = bid - 4096; }
  else if (bid < 4224) { w = uw;  wt = uwt;  K = 256;  N = 1024; gx = 16; l = bid - 4160; }
  else {
    size_t i = ((size_t)(bid - 4224) * 256 + t) * 4;
    f32x4 v = *(const f32x4*)&enc[i];
    ushort4v o;
#pragma unroll
    for (int j = 0; j < 4; ++j) o[j] = f2b(v[j]);
    *(ushort4v*)&encb[i] = o;
    return;
  }
  int bx = l % gx, by = l / gx;
  int tn = bx * 64, tk = by * 64;
  int c = t & 63, r0 = t >> 6;
#pragma unroll
  for (int p = 0; p < 16; ++p) {
    int r = r0 + p * 4;
    tile[r][c] = w[(size_t)(tk + r) * N + tn + c];
  }
  __syncthreads();
#pragma unroll
  for (int p = 0; p < 16; ++p) {
    int r = r0 + p * 4;
    wt[(size_t)(tn + r) * K + tk + c] = f2b(tile[c][r]);
  }
}

// ---------------- LayerNorm over C=1024, out bf16 ----------------
__global__ __launch_bounds__(256) void k_ln(const float* __restrict__ in,
                                            const float* __restrict__ g,
                                            const float* __restrict__ b,
                                            unsigned short* __restrict__ out) {
  int row = blockIdx.x;
  const float* x = in + (size_t)row * 1024;
  int t = threadIdx.x;
  float v0 = x[t], v1 = x[t + 256], v2 = x[t + 512], v3 = x[t + 768];
  float s = v0 + v1 + v2 + v3;
  float s2 = v0 * v0 + v1 * v1 + v2 * v2 + v3 * v3;
#pragma unroll
  for (int m = 1; m < 64; m <<= 1) { s += __shfl_xor(s, m); s2 += __shfl_xor(s2, m); }
  __shared__ float rs[4], rs2[4];
  int w = t >> 6;
  if ((t & 63) == 0) { rs[w] = s; rs2[w] = s2; }
  __syncthreads();
  s = rs[0] + rs[1] + rs[2] + rs[3];
  s2 = rs2[0] + rs2[1] + rs2[2] + rs2[3];
  float mean = s * (1.0f / 1024.0f);
  float var = s2 * (1.0f / 1024.0f) - mean * mean;
  float rinv = rsqrtf(var + 1e-5f);
  unsigned short* o = out + (size_t)row * 1024;
  o[t]       = f2b((v0 - mean) * rinv * g[t]       + b[t]);
  o[t + 256] = f2b((v1 - mean) * rinv * g[t + 256] + b[t + 256]);
  o[t + 512] = f2b((v2 - mean) * rinv * g[t + 512] + b[t + 512]);
  o[t + 768] = f2b((v3 - mean) * rinv * g[t + 768] + b[t + 768]);
}

// ---------------- 256x256 reg-staged double-buffered GEMM (T14 async-split) ----------------
// Per K-tile(64): issue next tile's global loads into VGPRs -> ds_read+MFMA cur ->
// ds_write next into OTHER buffer -> one barrier. LDS 128KB (2 x {A[256][64],B[256][64]}).
// XOR swizzle: row r, 16B-chunk c stored at slot c^(r&7)  (write & read sides; conflict-free).
template <bool GELU>
__global__ __launch_bounds__(512, 2) void k_g256r(
    const unsigned short* __restrict__ A, int lda,
    const unsigned short* __restrict__ W, int ldw,
    const float* __restrict__ bias,
    unsigned short* __restrict__ outB, int ldo, int K, int nbx) {
  __shared__ unsigned short lds[65536];   // 2 bufs x 32768 u16 (A 16384 + B 16384)
  const int t = threadIdx.x;
  const int swz = xcd_swz(blockIdx.x, gridDim.x);
  const int tileM = (swz / nbx) * 256, tileN = (swz % nbx) * 256;
  const int lane = t & 63, w = t >> 6;
  const int wm = w >> 2, wn = w & 3;
  const int lr16 = lane & 15, kc4 = lane >> 4;

  const int sr = t >> 1, hb = t & 1;           // staging: row, 32-k half
  const unsigned short* ga = A + (size_t)(tileM + sr) * lda + hb * 32;
  const unsigned short* gw = W + (size_t)(tileN + sr) * ldw + hb * 32;
  unsigned short* const wbA = &lds[sr * 64];   // + buf*32768 ; B at +16384
  const int wsl[4] = {((hb * 4 + 0) ^ (sr & 7)) * 8, ((hb * 4 + 1) ^ (sr & 7)) * 8,
                      ((hb * 4 + 2) ^ (sr & 7)) * 8, ((hb * 4 + 3) ^ (sr & 7)) * 8};

  f32x4 acc[8][4];
#pragma unroll
  for (int i = 0; i < 8; ++i)
#pragma unroll
    for (int j = 0; j < 4; ++j) acc[i][j] = f32x4{0.f, 0.f, 0.f, 0.f};

  const int nt = K >> 6;
  ushort8v ra[4], rb[4];

#define LOADT(T)                                              \
  do {                                                        \
    int ko = (T) << 6;                                        \
    _Pragma("unroll") for (int j = 0; j < 4; ++j) {           \
      ra[j] = *(const ushort8v*)(ga + ko + j * 8);            \
      rb[j] = *(const ushort8v*)(gw + ko + j * 8);            \
    }                                                         \
  } while (0)
#define WRITET(bsel)                                          \
  do {                                                        \
    unsigned short* dA = wbA + (bsel) * 32768;                \
    _Pragma("unroll") for (int j = 0; j < 4; ++j) {           \
      *(ushort8v*)(dA + wsl[j]) = ra[j];                      \
      *(ushort8v*)(dA + 16384 + wsl[j]) = rb[j];              \
    }                                                         \
  } while (0)

  LOADT(0);
  WRITET(0);
  __syncthreads();

  for (int T = 0; T < nt; ++T) {
    if (T + 1 < nt) LOADT(T + 1);
    const int base = (T & 1) * 32768;
#pragma unroll
    for (int ks = 0; ks < 2; ++ks) {
      short8v bfr[4];
#pragma unroll
      for (int n = 0; n < 4; ++n) {
        int r = wn * 64 + n * 16 + lr16;
        int sl = ((ks * 4 + kc4) ^ (r & 7)) * 8;
        bfr[n] = *(const short8v*)&lds[base + 16384 + r * 64 + sl];
      }
#pragma unroll
      for (int mi = 0; mi < 8; ++mi) {
        int r = wm * 128 + mi * 16 + lr16;
        int sl = ((ks * 4 + kc4) ^ (r & 7)) * 8;
        short8v af = *(const short8v*)&lds[base + r * 64 + sl];
#pragma unroll
        for (int n = 0; n < 4; ++n)
          acc[mi][n] = __builtin_amdgcn_mfma_f32_16x16x32_bf16(af, bfr[n], acc[mi][n], 0, 0, 0);
      }
    }
    if (T + 1 < nt) WRITET((T + 1) & 1);
    __syncthreads();
  }
#undef LOADT
#undef WRITET

#pragma unroll
  for (int mi = 0; mi < 8; ++mi) {
#pragma unroll
    for (int n = 0; n < 4; ++n) {
      int col = tileN + wn * 64 + n * 16 + lr16;
      float bv = bias[col];
#pragma unroll
      for (int qi = 0; qi < 4; ++qi) {
        int row = tileM + wm * 128 + mi * 16 + kc4 * 4 + qi;
        float v = acc[mi][n][qi] + bv;
        if (GELU) v = gelu_f(v);
        outB[(size_t)row * ldo + col] = f2b(v);
      }
    }
  }
}

// ---------------- 128x128 reg-staged double-buffered GEMM ----------------
// LDS 64KB (2 bufs x {A[128][64], B[128][64]}); same swizzle; 2 blocks/CU.
template <bool GELU, bool WF32, bool WBF16, int NRES, bool RES1B>
__global__ __launch_bounds__(256, 2) void k_g128r(
    const unsigned short* __restrict__ A, int lda,
    const unsigned short* __restrict__ W, int ldw,
    const float* __restrict__ bias,
    const float* __restrict__ res1, const unsigned short* __restrict__ res1b,
    const float* __restrict__ res2,
    float* __restrict__ outF, unsigned short* __restrict__ outB,
    int M, int N, int K, int nbx) {
  __shared__ unsigned short lds[32768];   // 2 bufs x 16384 u16 (A 8192 + B 8192)
  const int t = threadIdx.x;
  const int swz = xcd_swz(blockIdx.x, gridDim.x);
  const int tileM = (swz / nbx) * 128, tileN = (swz % nbx) * 128;
  const int lane = t & 63, w = t >> 6;
  const int wm = (w >> 1) * 64, wn = (w & 1) * 64;
  const int lr16 = lane & 15, kc4 = lane >> 4;

  const int sr = t >> 1, hb = t & 1;
  int gr = tileM + sr; if (gr >= M) gr = M - 1;
  const unsigned short* ga = A + (size_t)gr * lda + hb * 32;
  const unsigned short* gw = W + (size_t)(tileN + sr) * ldw + hb * 32;
  unsigned short* const wbA = &lds[sr * 64];
  const int wsl[4] = {((hb * 4 + 0) ^ (sr & 7)) * 8, ((hb * 4 + 1) ^ (sr & 7)) * 8,
                      ((hb * 4 + 2) ^ (sr & 7)) * 8, ((hb * 4 + 3) ^ (sr & 7)) * 8};

  f32x4 acc[4][4];
#pragma unroll
  for (int i = 0; i < 4; ++i)
#pragma unroll
    for (int j = 0; j < 4; ++j) acc[i][j] = f32x4{0.f, 0.f, 0.f, 0.f};

  const int nt = K >> 6;
  ushort8v ra[4], rb[4];

#define LOADT(T)                                              \
  do {                                                        \
    int ko = (T) << 6;                                        \
    _Pragma("unroll") for (int j = 0; j < 4; ++j) {           \
      ra[j] = *(const ushort8v*)(ga + ko + j * 8);            \
      rb[j] = *(const ushort8v*)(gw + ko + j * 8);            \
    }                                                         \
  } while (0)
#define WRITET(bsel)                                          \
  do {                                                        \
    unsigned short* dA = wbA + (bsel) * 16384;                \
    _Pragma("unroll") for (int j = 0; j < 4; ++j) {           \
      *(ushort8v*)(dA + wsl[j]) = ra[j];                      \
      *(ushort8v*)(dA + 8192 + wsl[j]) = rb[j];               \
    }                                                         \
  } while (0)

  LOADT(0);
  WRITET(0);
  __syncthreads();

  for (int T = 0; T < nt; ++T) {
    if (T + 1 < nt) LOADT(T + 1);
    const int base = (T & 1) * 16384;
#pragma unroll
    for (int ks = 0; ks < 2; ++ks) {
      short8v bfr[4];
#pragma unroll
      for (int n = 0; n < 4; ++n) {
        int r = wn + n * 16 + lr16;
        int sl = ((ks * 4 + kc4) ^ (r & 7)) * 8;
        bfr[n] = *(const short8v*)&lds[base + 8192 + r * 64 + sl];
      }
#pragma unroll
      for (int mi = 0; mi < 4; ++mi) {
        int r = wm + mi * 16 + lr16;
        int sl = ((ks * 4 + kc4) ^ (r & 7)) * 8;
        short8v af = *(const short8v*)&lds[base + r * 64 + sl];
#pragma unroll
        for (int n = 0; n < 4; ++n)
          acc[mi][n] = __builtin_amdgcn_mfma_f32_16x16x32_bf16(af, bfr[n], acc[mi][n], 0, 0, 0);
      }
    }
    if (T + 1 < nt) WRITET((T + 1) & 1);
    __syncthreads();
  }
#undef LOADT
#undef WRITET

#pragma unroll
  for (int mi = 0; mi < 4; ++mi) {
#pragma unroll
    for (int n = 0; n < 4; ++n) {
      int col = tileN + wn + n * 16 + lr16;
      float bv = bias[col];
#pragma unroll
      for (int qi = 0; qi < 4; ++qi) {
        int row = tileM + wm + mi * 16 + kc4 * 4 + qi;
        if (row < M) {
          float v = acc[mi][n][qi] + bv;
          if (GELU) v = gelu_f(v);
          size_t o = (size_t)row * N + col;
          if (NRES >= 1) v += RES1B ? b2f(res1b[o]) : res1[o];
          if (NRES >= 2) v += res2[o];
          if (WF32) outF[o] = v;
          if (WBF16) outB[o] = f2b(v);
        }
      }
    }
  }
}

// ---------------- V transpose: src[b*TB+tok][src_off+h*64+d] -> dst[bh][d][tok] ----------------
__global__ __launch_bounds__(256) void k_vtrans(const unsigned short* __restrict__ src,
                                                int src_stride, int src_off, int TB,
                                                unsigned short* __restrict__ dst, int dst_tstride) {
  __shared__ unsigned short tile[64][72];
  int tb = blockIdx.x, bh = blockIdx.y;
  int b = bh >> 4, h = bh & 15;
  int t = threadIdx.x;
  int r = t >> 2, c0 = (t & 3) * 16;
  int tok = tb * 64 + r; if (tok >= TB) tok = TB - 1;
  const unsigned short* s = src + (size_t)(b * TB + tok) * src_stride + src_off + h * 64 + c0;
  *(ushort8v*)&tile[r][c0] = *(const ushort8v*)s;
  *(ushort8v*)&tile[r][c0 + 8] = *(const ushort8v*)(s + 8);
  __syncthreads();
  unsigned short tmp[16];
#pragma unroll
  for (int j = 0; j < 16; ++j) tmp[j] = tile[c0 + j][r];
  unsigned short* dp = dst + ((size_t)bh * 64 + r) * dst_tstride + tb * 64 + c0;
  *(ushort8v*)dp = *(const ushort8v*)&tmp[0];
  *(ushort8v*)(dp + 8) = *(const ushort8v*)&tmp[8];
}

// ---------------- MFMA flash attention ----------------
template <bool CAUSAL>
__global__ __launch_bounds__(256) void k_attn(
    const unsigned short* __restrict__ Qb, int q_stride,
    const unsigned short* __restrict__ Kb, int k_stride, int k_off, int TKR,
    const unsigned short* __restrict__ Vt, int vt_tstride,
    unsigned short* __restrict__ out, int Tk) {
  __shared__ unsigned short Kl[64 * 72];
  __shared__ unsigned short Vl[64 * 72];
  __shared__ unsigned short Pl[4][16 * 72];
  const int swz = xcd_swz(blockIdx.x, gridDim.x);
  int qb = swz & 15, bh = swz >> 4;
  int b = bh >> 4, h = bh & 15;
  int t = threadIdx.x, lane = t & 63, w = t >> 6;
  int g = lane >> 4, lc = lane & 15;

  int qrow_g = qb * 64 + w * 16 + lc;
  const unsigned short* qp = Qb + (size_t)(b * 1024 + qrow_g) * q_stride + h * 64 + g * 8;
  short8v aq0 = *(const short8v*)qp;
  short8v aq1 = *(const short8v*)(qp + 32);

  f32x4 o[4];
  float m_[4], l_[4];
#pragma unroll
  for (int dt = 0; dt < 4; ++dt) o[dt] = f32x4{0.f, 0.f, 0.f, 0.f};
#pragma unroll
  for (int r = 0; r < 4; ++r) { m_[r] = -3.0e38f; l_[r] = 0.0f; }

  int srow = t >> 2;
  int sc = (t & 3) * 16;
  int ntiles = CAUSAL ? (qb + 1) : ((Tk + 63) >> 6);

  for (int kt = 0; kt < ntiles; ++kt) {
    __syncthreads();
    {
      int kg = kt * 64 + srow;
      if (!CAUSAL && kg >= Tk) kg = Tk - 1;
      const unsigned short* ks = Kb + (size_t)(b * TKR + kg) * k_stride + k_off + h * 64 + sc;
      *(ushort8v*)&Kl[srow * 72 + sc]     = *(const ushort8v*)ks;
      *(ushort8v*)&Kl[srow * 72 + sc + 8] = *(const ushort8v*)(ks + 8);
      const unsigned short* vs = Vt + ((size_t)bh * 64 + srow) * vt_tstride + kt * 64 + sc;
      *(ushort8v*)&Vl[srow * 72 + sc]     = *(const ushort8v*)vs;
      *(ushort8v*)&Vl[srow * 72 + sc + 8] = *(const ushort8v*)(vs + 8);
    }
    __syncthreads();

    f32x4 s[4];
#pragma unroll
    for (int jt = 0; jt < 4; ++jt) {
      short8v bk0 = *(const short8v*)&Kl[(jt * 16 + lc) * 72 + g * 8];
      short8v bk1 = *(const short8v*)&Kl[(jt * 16 + lc) * 72 + g * 8 + 32];
      f32x4 acc = f32x4{0.f, 0.f, 0.f, 0.f};
      acc = __builtin_amdgcn_mfma_f32_16x16x32_bf16(aq0, bk0, acc, 0, 0, 0);
      acc = __builtin_amdgcn_mfma_f32_16x16x32_bf16(aq1, bk1, acc, 0, 0, 0);
      s[jt] = acc;
    }
#pragma unroll
    for (int jt = 0; jt < 4; ++jt)
#pragma unroll
      for (int r = 0; r < 4; ++r) {
        float sv = s[jt][r] * 0.125f;
        bool masked = CAUSAL ? (kt == qb && (jt * 16 + lc) > (w * 16 + g * 4 + r))
                             : (kt * 64 + jt * 16 + lc >= Tk);
        s[jt][r] = masked ? -3.0e38f : sv;
      }
    float f[4];
#pragma unroll
    for (int r = 0; r < 4; ++r) {
      float mx = fmaxf(fmaxf(s[0][r], s[1][r]), fmaxf(s[2][r], s[3][r]));
      mx = fmaxf(mx, __shfl_xor(mx, 1));
      mx = fmaxf(mx, __shfl_xor(mx, 2));
      mx = fmaxf(mx, __shfl_xor(mx, 4));
      mx = fmaxf(mx, __shfl_xor(mx, 8));
      float mnew = fmaxf(m_[r], mx);
      f[r] = __expf(m_[r] - mnew);
      m_[r] = mnew;
      float rsum = 0.0f;
#pragma unroll
      for (int jt = 0; jt < 4; ++jt) {
        float p = __expf(s[jt][r] - mnew);
        s[jt][r] = p;
        rsum += p;
      }
      rsum += __shfl_xor(rsum, 1);
      rsum += __shfl_xor(rsum, 2);
      rsum += __shfl_xor(rsum, 4);
      rsum += __shfl_xor(rsum, 8);
      l_[r] = l_[r] * f[r] + rsum;
    }
#pragma unroll
    for (int dt = 0; dt < 4; ++dt)
#pragma unroll
      for (int r = 0; r < 4; ++r) o[dt][r] *= f[r];
#pragma unroll
    for (int jt = 0; jt < 4; ++jt)
#pragma unroll
      for (int r = 0; r < 4; ++r)
        Pl[w][(g * 4 + r) * 72 + jt * 16 + lc] = f2b(s[jt][r]);
    short8v ap0 = *(const short8v*)&Pl[w][lc * 72 + g * 8];
    short8v ap1 = *(const short8v*)&Pl[w][lc * 72 + g * 8 + 32];
#pragma unroll
    for (int dt = 0; dt < 4; ++dt) {
      short8v bv0 = *(const short8v*)&Vl[(dt * 16 + lc) * 72 + g * 8];
      short8v bv1 = *(const short8v*)&Vl[(dt * 16 + lc) * 72 + g * 8 + 32];
      o[dt] = __builtin_amdgcn_mfma_f32_16x16x32_bf16(ap0, bv0, o[dt], 0, 0, 0);
      o[dt] = __builtin_amdgcn_mfma_f32_16x16x32_bf16(ap1, bv1, o[dt], 0, 0, 0);
    }
  }
  size_t orow = (size_t)(b * 1024 + qb * 64 + w * 16) * 1024 + h * 64;
#pragma unroll
  for (int r = 0; r < 4; ++r) {
    float inv = 1.0f / l_[r];
#pragma unroll
    for (int dt = 0; dt < 4; ++dt)
      out[orow + (size_t)(g * 4 + r) * 1024 + dt * 16 + lc] = f2b(o[dt][r] * inv);
  }
}

extern "C" void kernel_launch(void* const* d_in, const int* in_sizes, int n_in,
                              void* d_out, int out_size, void* d_ws, size_t ws_size,
                              hipStream_t stream) {
  (void)in_sizes; (void)n_in; (void)out_size; (void)ws_size;
  const float* x       = (const float*)d_in[0];
  const float* enc     = (const float*)d_in[1];
  const float* ln1_g   = (const float*)d_in[3];
  const float* ln1_b   = (const float*)d_in[4];
  const float* ln2_g   = (const float*)d_in[5];
  const float* ln2_b   = (const float*)d_in[6];
  const float* ln3_g   = (const float*)d_in[7];
  const float* ln3_b   = (const float*)d_in[8];
  const float* attn_w  = (const float*)d_in[9];
  const float* attn_b  = (const float*)d_in[10];
  const float* aproj_w = (const float*)d_in[11];
  const float* aproj_b = (const float*)d_in[12];
  const float* ca_w    = (const float*)d_in[13];
  const float* ca_b    = (const float*)d_in[14];
  const float* caproj_w= (const float*)d_in[15];
  const float* caproj_b= (const float*)d_in[16];
  const float* fc_w    = (const float*)d_in[17];
  const float* fc_b    = (const float*)d_in[18];
  const float* mproj_w = (const float*)d_in[19];
  const float* mproj_b = (const float*)d_in[20];
  const float* down_w  = (const float*)d_in[21];
  const float* down_b  = (const float*)d_in[22];
  const float* up_w    = (const float*)d_in[23];
  const float* up_b    = (const float*)d_in[24];
  float* out = (float*)d_out;
  char* ws = (char*)d_ws;

  const size_t O_WATTN = 0, O_WAPROJ = 6291456, O_WCA = 8388608, O_WCAPROJ = 14680064,
               O_WFC = 16777216, O_WMPROJ = 25165824, O_WDOWN = 33554432, O_WUP = 34078720,
               O_ENC = 34603008, O_LN = 36708352, O_BIG = 45096960,
               O_XRES = 78651392, O_ATTN = 112205824;

  unsigned short* wt_attn   = (unsigned short*)(ws + O_WATTN);
  unsigned short* wt_aproj  = (unsigned short*)(ws + O_WAPROJ);
  unsigned short* wt_ca     = (unsigned short*)(ws + O_WCA);
  unsigned short* wt_caproj = (unsigned short*)(ws + O_WCAPROJ);
  unsigned short* wt_fc     = (unsigned short*)(ws + O_WFC);
  unsigned short* wt_mproj  = (unsigned short*)(ws + O_WMPROJ);
  unsigned short* wt_down   = (unsigned short*)(ws + O_WDOWN);
  unsigned short* wt_up     = (unsigned short*)(ws + O_WUP);
  unsigned short* encbf     = (unsigned short*)(ws + O_ENC);
  unsigned short* lnout     = (unsigned short*)(ws + O_LN);
  unsigned short* hbf       = (unsigned short*)(ws + O_LN);            // after fc consumed
  unsigned short* qkvb      = (unsigned short*)(ws + O_BIG);
  unsigned short* vt_self   = (unsigned short*)(ws + O_BIG + 25165824); // alive with qkvb
  unsigned short* q2b       = (unsigned short*)(ws + O_BIG);           // after self path done
  unsigned short* kvb       = (unsigned short*)(ws + O_BIG + 8388608);
  unsigned short* vt_cross  = (unsigned short*)(ws + O_BIG + 12599296);
  unsigned short* caout     = (unsigned short*)(ws + O_BIG + 15220736);
  unsigned short* fcout     = (unsigned short*)(ws + O_BIG);           // after cross path done
  float*          xres      = (float*)(ws + O_XRES);
  unsigned short* attnout   = (unsigned short*)(ws + O_ATTN);
  unsigned short* dmid      = (unsigned short*)(ws + O_ATTN);          // after aproj consumed

  dim3 blk(256);
  dim3 blk5(512);

  // 1. merged weight prep (8 transposes + enc cvt)
  k_wprep<<<dim3(5252), blk, 0, stream>>>(
      attn_w, wt_attn, aproj_w, wt_aproj, ca_w, wt_ca, caproj_w, wt_caproj,
      fc_w, wt_fc, mproj_w, wt_mproj, down_w, wt_down, up_w, wt_up, enc, encbf);

  // 3. ln1(x) ; qkv ; V-transpose ; self-attn ; aproj + residual(x) -> xres
  k_ln<<<dim3(4096), blk, 0, stream>>>(x, ln1_g, ln1_b, lnout);
  k_g256r<false><<<dim3(192), blk5, 0, stream>>>(
      lnout, 1024, wt_attn, 1024, attn_b, qkvb, 3072, 1024, 12);
  k_vtrans<<<dim3(16, 64), blk, 0, stream>>>(qkvb, 3072, 2048, 1024, vt_self, 1024);
  k_attn<true><<<dim3(1024), blk, 0, stream>>>(
      qkvb, 3072, qkvb, 3072, 1024, 1024, vt_self, 1024, attnout, 1024);
  k_g128r<false, true, false, 1, false><<<dim3(256), blk, 0, stream>>>(
      attnout, 1024, wt_aproj, 1024, aproj_b, x, nullptr, nullptr, xres, nullptr,
      4096, 1024, 1024, 8);

  // 4. ln2(xres) ; q2 ; kv(enc) ; V-transpose ; cross-attn ; caproj + residual -> xres
  k_ln<<<dim3(4096), blk, 0, stream>>>(xres, ln2_g, ln2_b, lnout);
  k_g128r<false, false, true, 0, false><<<dim3(256), blk, 0, stream>>>(
      lnout, 1024, wt_ca, 1024, ca_b, nullptr, nullptr, nullptr, nullptr, q2b,
      4096, 1024, 1024, 8);
  k_g128r<false, false, true, 0, false><<<dim3(144), blk, 0, stream>>>(
      encbf, 1024, wt_ca + (size_t)1024 * 1024, 1024, ca_b + 1024, nullptr, nullptr,
      nullptr, nullptr, kvb, 1028, 2048, 1024, 16);
  k_vtrans<<<dim3(5, 64), blk, 0, stream>>>(kvb, 2048, 1024, 257, vt_cross, 320);
  k_attn<false><<<dim3(1024), blk, 0, stream>>>(
      q2b, 1024, kvb, 2048, 0, 257, vt_cross, 320, caout, 257);
  k_g128r<false, true, false, 1, false><<<dim3(256), blk, 0, stream>>>(
      caout, 1024, wt_caproj, 1024, caproj_b, xres, nullptr, nullptr, xres, nullptr,
      4096, 1024, 1024, 8);

  // 5. ln3(xres) ; fc+gelu ; mproj -> hbf
  k_ln<<<dim3(4096), blk, 0, stream>>>(xres, ln3_g, ln3_b, lnout);
  k_g256r<true><<<dim3(256), blk5, 0, stream>>>(
      lnout, 1024, wt_fc, 1024, fc_b, fcout, 4096, 1024, 16);
  k_g128r<false, false, true, 0, false><<<dim3(256), blk, 0, stream>>>(
      fcout, 4096, wt_mproj, 4096, mproj_b, nullptr, nullptr, nullptr, nullptr, hbf,
      4096, 1024, 4096, 8);

  // 6. adapter: down+gelu ; up + up_b + h(bf16) + xres -> out
  k_g128r<true, false, true, 0, false><<<dim3(64), blk, 0, stream>>>(
      hbf, 1024, wt_down, 1024, down_b, nullptr, nullptr, nullptr, nullptr, dmid,
      4096, 256, 1024, 2);
  k_g128r<false, true, false, 2, true><<<dim3(256), blk, 0, stream>>>(
      dmid, 256, wt_up, 256, up_b, nullptr, hbf, xres, out, nullptr,
      4096, 1024, 256, 8);
}

// Round 10
// 456.196 us; speedup vs baseline: 1.1191x; 1.0361x over previous
//
#include <hip/hip_runtime.h>

typedef __attribute__((ext_vector_type(8))) short short8v;
typedef __attribute__((ext_vector_type(8))) unsigned short ushort8v;
typedef __attribute__((ext_vector_type(4))) unsigned short ushort4v;
typedef __attribute__((ext_vector_type(4))) float f32x4;

__device__ __forceinline__ unsigned short f2b(float f) {
  unsigned int u = __float_as_uint(f);
  unsigned int r = (u + 0x7FFFu + ((u >> 16) & 1u)) >> 16;
  return (unsigned short)r;
}
__device__ __forceinline__ float b2f(unsigned short h) {
  return __uint_as_float(((unsigned int)h) << 16);
}
__device__ __forceinline__ float gelu_f(float x) {
  float z = 0.7978845608028654f * (x + 0.044715f * x * x * x);
  float e = __expf(2.0f * z);
  float t = 1.0f - 2.0f / (e + 1.0f);
  return 0.5f * x * (1.0f + t);
}
// bijective XCD swizzle (m204)
__device__ __forceinline__ int xcd_swz(int wgid, int nwg) {
  int q = nwg >> 3, r = nwg & 7;
  int xcd = wgid & 7, idx = wgid >> 3;
  return (xcd < r ? xcd * (q + 1) : r * (q + 1) + (xcd - r) * q) + idx;
}

// ---------------- merged weight prep: 8 transposes (f32 [K][N] -> bf16 [N][K]) + enc cvt ----
__global__ __launch_bounds__(256) void k_wprep(
    const float* aw, unsigned short* awt,
    const float* apw, unsigned short* apwt,
    const float* cw, unsigned short* cwt,
    const float* cpw, unsigned short* cpwt,
    const float* fw, unsigned short* fwt,
    const float* mw, unsigned short* mwt,
    const float* dw, unsigned short* dwt,
    const float* uw, unsigned short* uwt,
    const float* enc, unsigned short* encb) {
  __shared__ float tile[64][65];
  int bid = blockIdx.x, t = threadIdx.x;
  const float* w; unsigned short* wt; int K, N, gx, l;
  if      (bid < 768)  { w = aw;  wt = awt;  K = 1024; N = 3072; gx = 48; l = bid; }
  else if (bid < 1024) { w = apw; wt = apwt; K = 1024; N = 1024; gx = 16; l = bid - 768; }
  else if (bid < 1792) { w = cw;  wt = cwt;  K = 1024; N = 3072; gx = 48; l = bid - 1024; }
  else if (bid < 2048) { w = cpw; wt = cpwt; K = 1024; N = 1024; gx = 16; l = bid - 1792; }
  else if (bid < 3072) { w = fw;  wt = fwt;  K = 1024; N = 4096; gx = 64; l = bid - 2048; }
  else if (bid < 4096) { w = mw;  wt = mwt;  K = 4096; N = 1024; gx = 16; l = bid - 3072; }
  else if (bid < 4160) { w = dw;  wt = dwt;  K = 1024; N = 256;  gx = 4;  l = bid - 4096; }
  else if (bid < 4224) { w = uw;  wt = uwt;  K = 256;  N = 1024; gx = 16; l = bid - 4160; }
  else {
    size_t i = ((size_t)(bid - 4224) * 256 + t) * 4;
    f32x4 v = *(const f32x4*)&enc[i];
    ushort4v o;
#pragma unroll
    for (int j = 0; j < 4; ++j) o[j] = f2b(v[j]);
    *(ushort4v*)&encb[i] = o;
    return;
  }
  int bx = l % gx, by = l / gx;
  int tn = bx * 64, tk = by * 64;
  int c = t & 63, r0 = t >> 6;
#pragma unroll
  for (int p = 0; p < 16; ++p) {
    int r = r0 + p * 4;
    tile[r][c] = w[(size_t)(tk + r) * N + tn + c];
  }
  __syncthreads();
#pragma unroll
  for (int p = 0; p < 16; ++p) {
    int r = r0 + p * 4;
    wt[(size_t)(tn + r) * K + tk + c] = f2b(tile[c][r]);
  }
}

// ---------------- LayerNorm over C=1024, out bf16 ----------------
__global__ __launch_bounds__(256) void k_ln(const float* __restrict__ in,
                                            const float* __restrict__ g,
                                            const float* __restrict__ b,
                                            unsigned short* __restrict__ out) {
  int row = blockIdx.x;
  const float* x = in + (size_t)row * 1024;
  int t = threadIdx.x;
  float v0 = x[t], v1 = x[t + 256], v2 = x[t + 512], v3 = x[t + 768];
  float s = v0 + v1 + v2 + v3;
  float s2 = v0 * v0 + v1 * v1 + v2 * v2 + v3 * v3;
#pragma unroll
  for (int m = 1; m < 64; m <<= 1) { s += __shfl_xor(s, m); s2 += __shfl_xor(s2, m); }
  __shared__ float rs[4], rs2[4];
  int w = t >> 6;
  if ((t & 63) == 0) { rs[w] = s; rs2[w] = s2; }
  __syncthreads();
  s = rs[0] + rs[1] + rs[2] + rs[3];
  s2 = rs2[0] + rs2[1] + rs2[2] + rs2[3];
  float mean = s * (1.0f / 1024.0f);
  float var = s2 * (1.0f / 1024.0f) - mean * mean;
  float rinv = rsqrtf(var + 1e-5f);
  unsigned short* o = out + (size_t)row * 1024;
  o[t]       = f2b((v0 - mean) * rinv * g[t]       + b[t]);
  o[t + 256] = f2b((v1 - mean) * rinv * g[t + 256] + b[t + 256]);
  o[t + 512] = f2b((v2 - mean) * rinv * g[t + 512] + b[t + 512]);
  o[t + 768] = f2b((v3 - mean) * rinv * g[t + 768] + b[t + 768]);
}

// ---------------- 128x128 reg-staged GEMM, register prefetch distance 2 ----------------
// iter T: LOADT(T+2)->set[T&1] ; compute buf[T&1] ; WRITET(set[(T+1)&1])->buf[(T+1)&1] ; bar.
// ~2 full K-tiles (~5000 cyc) between global-load issue and ds_write consumption.
// LDS 64KB (2 bufs x {A[128][64], B[128][64]}); XOR swizzle slot c^(r&7) both sides.
template <bool GELU, bool WF32, bool WBF16, int NRES, bool RES1B>
__global__ __launch_bounds__(256, 2) void k_g128r(
    const unsigned short* __restrict__ A, int lda,
    const unsigned short* __restrict__ W, int ldw,
    const float* __restrict__ bias,
    const float* __restrict__ res1, const unsigned short* __restrict__ res1b,
    const float* __restrict__ res2,
    float* __restrict__ outF, unsigned short* __restrict__ outB,
    int M, int N, int K, int nbx) {
  __shared__ unsigned short lds[32768];   // 2 bufs x 16384 u16 (A 8192 + B 8192)
  const int t = threadIdx.x;
  const int swz = xcd_swz(blockIdx.x, gridDim.x);
  const int tileM = (swz / nbx) * 128, tileN = (swz % nbx) * 128;
  const int lane = t & 63, w = t >> 6;
  const int wm = (w >> 1) * 64, wn = (w & 1) * 64;
  const int lr16 = lane & 15, kc4 = lane >> 4;

  const int sr = t >> 1, hb = t & 1;
  int gr = tileM + sr; if (gr >= M) gr = M - 1;
  const unsigned short* ga = A + (size_t)gr * lda + hb * 32;
  const unsigned short* gw = W + (size_t)(tileN + sr) * ldw + hb * 32;
  unsigned short* const wbA = &lds[sr * 64];
  const int wsl[4] = {((hb * 4 + 0) ^ (sr & 7)) * 8, ((hb * 4 + 1) ^ (sr & 7)) * 8,
                      ((hb * 4 + 2) ^ (sr & 7)) * 8, ((hb * 4 + 3) ^ (sr & 7)) * 8};

  f32x4 acc[4][4];
#pragma unroll
  for (int i = 0; i < 4; ++i)
#pragma unroll
    for (int j = 0; j < 4; ++j) acc[i][j] = f32x4{0.f, 0.f, 0.f, 0.f};

  const int nt = K >> 6;   // always even here (K multiple of 128... min K=256)
  ushort8v raE[4], rbE[4], raO[4], rbO[4];

#define LOADT(T, ra, rb)                                      \
  do {                                                        \
    int ko = (T) << 6;                                        \
    _Pragma("unroll") for (int j = 0; j < 4; ++j) {           \
      ra[j] = *(const ushort8v*)(ga + ko + j * 8);            \
      rb[j] = *(const ushort8v*)(gw + ko + j * 8);            \
    }                                                         \
  } while (0)
#define WRITET(ra, rb, bsel)                                  \
  do {                                                        \
    unsigned short* dA = wbA + (bsel) * 16384;                \
    _Pragma("unroll") for (int j = 0; j < 4; ++j) {           \
      *(ushort8v*)(dA + wsl[j]) = ra[j];                      \
      *(ushort8v*)(dA + 8192 + wsl[j]) = rb[j];               \
    }                                                         \
  } while (0)
#define COMPUTE(bsel)                                                           \
  do {                                                                          \
    const int base = (bsel) * 16384;                                            \
    _Pragma("unroll") for (int ks = 0; ks < 2; ++ks) {                          \
      short8v bfr[4];                                                           \
      _Pragma("unroll") for (int n = 0; n < 4; ++n) {                           \
        int r = wn + n * 16 + lr16;                                             \
        int sl = ((ks * 4 + kc4) ^ (r & 7)) * 8;                                \
        bfr[n] = *(const short8v*)&lds[base + 8192 + r * 64 + sl];              \
      }                                                                         \
      _Pragma("unroll") for (int mi = 0; mi < 4; ++mi) {                        \
        int r = wm + mi * 16 + lr16;                                            \
        int sl = ((ks * 4 + kc4) ^ (r & 7)) * 8;                                \
        short8v af = *(const short8v*)&lds[base + r * 64 + sl];                 \
        _Pragma("unroll") for (int n = 0; n < 4; ++n)                           \
          acc[mi][n] =                                                          \
              __builtin_amdgcn_mfma_f32_16x16x32_bf16(af, bfr[n], acc[mi][n], 0, 0, 0); \
      }                                                                         \
    }                                                                           \
  } while (0)

  LOADT(0, raE, rbE);
  WRITET(raE, rbE, 0);
  if (nt > 1) LOADT(1, raO, rbO);
  __syncthreads();

  for (int T = 0; T < nt; T += 2) {
    // even iter T: compute buf0; prefetch T+2 into E; write O(tile T+1) -> buf1
    if (T + 2 < nt) LOADT(T + 2, raE, rbE);
    COMPUTE(0);
    if (T + 1 < nt) WRITET(raO, rbO, 1);
    __syncthreads();
    if (T + 1 < nt) {
      // odd iter T+1: compute buf1; prefetch T+3 into O; write E(tile T+2) -> buf0
      if (T + 3 < nt) LOADT(T + 3, raO, rbO);
      COMPUTE(1);
      if (T + 2 < nt) WRITET(raE, rbE, 0);
      __syncthreads();
    }
  }
#undef LOADT
#undef WRITET
#undef COMPUTE

#pragma unroll
  for (int mi = 0; mi < 4; ++mi) {
#pragma unroll
    for (int n = 0; n < 4; ++n) {
      int col = tileN + wn + n * 16 + lr16;
      float bv = bias[col];
#pragma unroll
      for (int qi = 0; qi < 4; ++qi) {
        int row = tileM + wm + mi * 16 + kc4 * 4 + qi;
        if (row < M) {
          float v = acc[mi][n][qi] + bv;
          if (GELU) v = gelu_f(v);
          size_t o = (size_t)row * N + col;
          if (NRES >= 1) v += RES1B ? b2f(res1b[o]) : res1[o];
          if (NRES >= 2) v += res2[o];
          if (WF32) outF[o] = v;
          if (WBF16) outB[o] = f2b(v);
        }
      }
    }
  }
}

// ---------------- V transpose: src[b*TB+tok][src_off+h*64+d] -> dst[bh][d][tok] ----------------
__global__ __launch_bounds__(256) void k_vtrans(const unsigned short* __restrict__ src,
                                                int src_stride, int src_off, int TB,
                                                unsigned short* __restrict__ dst, int dst_tstride) {
  __shared__ unsigned short tile[64][72];
  int tb = blockIdx.x, bh = blockIdx.y;
  int b = bh >> 4, h = bh & 15;
  int t = threadIdx.x;
  int r = t >> 2, c0 = (t & 3) * 16;
  int tok = tb * 64 + r; if (tok >= TB) tok = TB - 1;
  const unsigned short* s = src + (size_t)(b * TB + tok) * src_stride + src_off + h * 64 + c0;
  *(ushort8v*)&tile[r][c0] = *(const ushort8v*)s;
  *(ushort8v*)&tile[r][c0 + 8] = *(const ushort8v*)(s + 8);
  __syncthreads();
  unsigned short tmp[16];
#pragma unroll
  for (int j = 0; j < 16; ++j) tmp[j] = tile[c0 + j][r];
  unsigned short* dp = dst + ((size_t)bh * 64 + r) * dst_tstride + tb * 64 + c0;
  *(ushort8v*)dp = *(const ushort8v*)&tmp[0];
  *(ushort8v*)(dp + 8) = *(const ushort8v*)&tmp[8];
}

// ---------------- MFMA flash attention ----------------
template <bool CAUSAL>
__global__ __launch_bounds__(256) void k_attn(
    const unsigned short* __restrict__ Qb, int q_stride,
    const unsigned short* __restrict__ Kb, int k_stride, int k_off, int TKR,
    const unsigned short* __restrict__ Vt, int vt_tstride,
    unsigned short* __restrict__ out, int Tk) {
  __shared__ unsigned short Kl[64 * 72];
  __shared__ unsigned short Vl[64 * 72];
  __shared__ unsigned short Pl[4][16 * 72];
  const int swz = xcd_swz(blockIdx.x, gridDim.x);
  int qb = swz & 15, bh = swz >> 4;
  int b = bh >> 4, h = bh & 15;
  int t = threadIdx.x, lane = t & 63, w = t >> 6;
  int g = lane >> 4, lc = lane & 15;

  int qrow_g = qb * 64 + w * 16 + lc;
  const unsigned short* qp = Qb + (size_t)(b * 1024 + qrow_g) * q_stride + h * 64 + g * 8;
  short8v aq0 = *(const short8v*)qp;
  short8v aq1 = *(const short8v*)(qp + 32);

  f32x4 o[4];
  float m_[4], l_[4];
#pragma unroll
  for (int dt = 0; dt < 4; ++dt) o[dt] = f32x4{0.f, 0.f, 0.f, 0.f};
#pragma unroll
  for (int r = 0; r < 4; ++r) { m_[r] = -3.0e38f; l_[r] = 0.0f; }

  int srow = t >> 2;
  int sc = (t & 3) * 16;
  int ntiles = CAUSAL ? (qb + 1) : ((Tk + 63) >> 6);

  for (int kt = 0; kt < ntiles; ++kt) {
    __syncthreads();
    {
      int kg = kt * 64 + srow;
      if (!CAUSAL && kg >= Tk) kg = Tk - 1;
      const unsigned short* ks = Kb + (size_t)(b * TKR + kg) * k_stride + k_off + h * 64 + sc;
      *(ushort8v*)&Kl[srow * 72 + sc]     = *(const ushort8v*)ks;
      *(ushort8v*)&Kl[srow * 72 + sc + 8] = *(const ushort8v*)(ks + 8);
      const unsigned short* vs = Vt + ((size_t)bh * 64 + srow) * vt_tstride + kt * 64 + sc;
      *(ushort8v*)&Vl[srow * 72 + sc]     = *(const ushort8v*)vs;
      *(ushort8v*)&Vl[srow * 72 + sc + 8] = *(const ushort8v*)(vs + 8);
    }
    __syncthreads();

    f32x4 s[4];
#pragma unroll
    for (int jt = 0; jt < 4; ++jt) {
      short8v bk0 = *(const short8v*)&Kl[(jt * 16 + lc) * 72 + g * 8];
      short8v bk1 = *(const short8v*)&Kl[(jt * 16 + lc) * 72 + g * 8 + 32];
      f32x4 acc = f32x4{0.f, 0.f, 0.f, 0.f};
      acc = __builtin_amdgcn_mfma_f32_16x16x32_bf16(aq0, bk0, acc, 0, 0, 0);
      acc = __builtin_amdgcn_mfma_f32_16x16x32_bf16(aq1, bk1, acc, 0, 0, 0);
      s[jt] = acc;
    }
#pragma unroll
    for (int jt = 0; jt < 4; ++jt)
#pragma unroll
      for (int r = 0; r < 4; ++r) {
        float sv = s[jt][r] * 0.125f;
        bool masked = CAUSAL ? (kt == qb && (jt * 16 + lc) > (w * 16 + g * 4 + r))
                             : (kt * 64 + jt * 16 + lc >= Tk);
        s[jt][r] = masked ? -3.0e38f : sv;
      }
    float f[4];
#pragma unroll
    for (int r = 0; r < 4; ++r) {
      float mx = fmaxf(fmaxf(s[0][r], s[1][r]), fmaxf(s[2][r], s[3][r]));
      mx = fmaxf(mx, __shfl_xor(mx, 1));
      mx = fmaxf(mx, __shfl_xor(mx, 2));
      mx = fmaxf(mx, __shfl_xor(mx, 4));
      mx = fmaxf(mx, __shfl_xor(mx, 8));
      float mnew = fmaxf(m_[r], mx);
      f[r] = __expf(m_[r] - mnew);
      m_[r] = mnew;
      float rsum = 0.0f;
#pragma unroll
      for (int jt = 0; jt < 4; ++jt) {
        float p = __expf(s[jt][r] - mnew);
        s[jt][r] = p;
        rsum += p;
      }
      rsum += __shfl_xor(rsum, 1);
      rsum += __shfl_xor(rsum, 2);
      rsum += __shfl_xor(rsum, 4);
      rsum += __shfl_xor(rsum, 8);
      l_[r] = l_[r] * f[r] + rsum;
    }
#pragma unroll
    for (int dt = 0; dt < 4; ++dt)
#pragma unroll
      for (int r = 0; r < 4; ++r) o[dt][r] *= f[r];
#pragma unroll
    for (int jt = 0; jt < 4; ++jt)
#pragma unroll
      for (int r = 0; r < 4; ++r)
        Pl[w][(g * 4 + r) * 72 + jt * 16 + lc] = f2b(s[jt][r]);
    short8v ap0 = *(const short8v*)&Pl[w][lc * 72 + g * 8];
    short8v ap1 = *(const short8v*)&Pl[w][lc * 72 + g * 8 + 32];
#pragma unroll
    for (int dt = 0; dt < 4; ++dt) {
      short8v bv0 = *(const short8v*)&Vl[(dt * 16 + lc) * 72 + g * 8];
      short8v bv1 = *(const short8v*)&Vl[(dt * 16 + lc) * 72 + g * 8 + 32];
      o[dt] = __builtin_amdgcn_mfma_f32_16x16x32_bf16(ap0, bv0, o[dt], 0, 0, 0);
      o[dt] = __builtin_amdgcn_mfma_f32_16x16x32_bf16(ap1, bv1, o[dt], 0, 0, 0);
    }
  }
  size_t orow = (size_t)(b * 1024 + qb * 64 + w * 16) * 1024 + h * 64;
#pragma unroll
  for (int r = 0; r < 4; ++r) {
    float inv = 1.0f / l_[r];
#pragma unroll
    for (int dt = 0; dt < 4; ++dt)
      out[orow + (size_t)(g * 4 + r) * 1024 + dt * 16 + lc] = f2b(o[dt][r] * inv);
  }
}

extern "C" void kernel_launch(void* const* d_in, const int* in_sizes, int n_in,
                              void* d_out, int out_size, void* d_ws, size_t ws_size,
                              hipStream_t stream) {
  (void)in_sizes; (void)n_in; (void)out_size; (void)ws_size;
  const float* x       = (const float*)d_in[0];
  const float* enc     = (const float*)d_in[1];
  const float* ln1_g   = (const float*)d_in[3];
  const float* ln1_b   = (const float*)d_in[4];
  const float* ln2_g   = (const float*)d_in[5];
  const float* ln2_b   = (const float*)d_in[6];
  const float* ln3_g   = (const float*)d_in[7];
  const float* ln3_b   = (const float*)d_in[8];
  const float* attn_w  = (const float*)d_in[9];
  const float* attn_b  = (const float*)d_in[10];
  const float* aproj_w = (const float*)d_in[11];
  const float* aproj_b = (const float*)d_in[12];
  const float* ca_w    = (const float*)d_in[13];
  const float* ca_b    = (const float*)d_in[14];
  const float* caproj_w= (const float*)d_in[15];
  const float* caproj_b= (const float*)d_in[16];
  const float* fc_w    = (const float*)d_in[17];
  const float* fc_b    = (const float*)d_in[18];
  const float* mproj_w = (const float*)d_in[19];
  const float* mproj_b = (const float*)d_in[20];
  const float* down_w  = (const float*)d_in[21];
  const float* down_b  = (const float*)d_in[22];
  const float* up_w    = (const float*)d_in[23];
  const float* up_b    = (const float*)d_in[24];
  float* out = (float*)d_out;
  char* ws = (char*)d_ws;

  const size_t O_WATTN = 0, O_WAPROJ = 6291456, O_WCA = 8388608, O_WCAPROJ = 14680064,
               O_WFC = 16777216, O_WMPROJ = 25165824, O_WDOWN = 33554432, O_WUP = 34078720,
               O_ENC = 34603008, O_LN = 36708352, O_BIG = 45096960,
               O_XRES = 78651392, O_ATTN = 112205824;

  unsigned short* wt_attn   = (unsigned short*)(ws + O_WATTN);
  unsigned short* wt_aproj  = (unsigned short*)(ws + O_WAPROJ);
  unsigned short* wt_ca     = (unsigned short*)(ws + O_WCA);
  unsigned short* wt_caproj = (unsigned short*)(ws + O_WCAPROJ);
  unsigned short* wt_fc     = (unsigned short*)(ws + O_WFC);
  unsigned short* wt_mproj  = (unsigned short*)(ws + O_WMPROJ);
  unsigned short* wt_down   = (unsigned short*)(ws + O_WDOWN);
  unsigned short* wt_up     = (unsigned short*)(ws + O_WUP);
  unsigned short* encbf     = (unsigned short*)(ws + O_ENC);
  unsigned short* lnout     = (unsigned short*)(ws + O_LN);
  unsigned short* hbf       = (unsigned short*)(ws + O_LN);            // after fc consumed
  unsigned short* qkvb      = (unsigned short*)(ws + O_BIG);
  unsigned short* vt_self   = (unsigned short*)(ws + O_BIG + 25165824); // alive with qkvb
  unsigned short* q2b       = (unsigned short*)(ws + O_BIG);           // after self path done
  unsigned short* kvb       = (unsigned short*)(ws + O_BIG + 8388608);
  unsigned short* vt_cross  = (unsigned short*)(ws + O_BIG + 12599296);
  unsigned short* caout     = (unsigned short*)(ws + O_BIG + 15220736);
  unsigned short* fcout     = (unsigned short*)(ws + O_BIG);           // after cross path done
  float*          xres      = (float*)(ws + O_XRES);
  unsigned short* attnout   = (unsigned short*)(ws + O_ATTN);
  unsigned short* dmid      = (unsigned short*)(ws + O_ATTN);          // after aproj consumed

  dim3 blk(256);

  // 1. merged weight prep (8 transposes + enc cvt)
  k_wprep<<<dim3(5252), blk, 0, stream>>>(
      attn_w, wt_attn, aproj_w, wt_aproj, ca_w, wt_ca, caproj_w, wt_caproj,
      fc_w, wt_fc, mproj_w, wt_mproj, down_w, wt_down, up_w, wt_up, enc, encbf);

  // 3. ln1(x) ; qkv ; V-transpose ; self-attn ; aproj + residual(x) -> xres
  k_ln<<<dim3(4096), blk, 0, stream>>>(x, ln1_g, ln1_b, lnout);
  k_g128r<false, false, true, 0, false><<<dim3(768), blk, 0, stream>>>(
      lnout, 1024, wt_attn, 1024, attn_b, nullptr, nullptr, nullptr, nullptr, qkvb,
      4096, 3072, 1024, 24);
  k_vtrans<<<dim3(16, 64), blk, 0, stream>>>(qkvb, 3072, 2048, 1024, vt_self, 1024);
  k_attn<true><<<dim3(1024), blk, 0, stream>>>(
      qkvb, 3072, qkvb, 3072, 1024, 1024, vt_self, 1024, attnout, 1024);
  k_g128r<false, true, false, 1, false><<<dim3(256), blk, 0, stream>>>(
      attnout, 1024, wt_aproj, 1024, aproj_b, x, nullptr, nullptr, xres, nullptr,
      4096, 1024, 1024, 8);

  // 4. ln2(xres) ; q2 ; kv(enc) ; V-transpose ; cross-attn ; caproj + residual -> xres
  k_ln<<<dim3(4096), blk, 0, stream>>>(xres, ln2_g, ln2_b, lnout);
  k_g128r<false, false, true, 0, false><<<dim3(256), blk, 0, stream>>>(
      lnout, 1024, wt_ca, 1024, ca_b, nullptr, nullptr, nullptr, nullptr, q2b,
      4096, 1024, 1024, 8);
  k_g128r<false, false, true, 0, false><<<dim3(144), blk, 0, stream>>>(
      encbf, 1024, wt_ca + (size_t)1024 * 1024, 1024, ca_b + 1024, nullptr, nullptr,
      nullptr, nullptr, kvb, 1028, 2048, 1024, 16);
  k_vtrans<<<dim3(5, 64), blk, 0, stream>>>(kvb, 2048, 1024, 257, vt_cross, 320);
  k_attn<false><<<dim3(1024), blk, 0, stream>>>(
      q2b, 1024, kvb, 2048, 0, 257, vt_cross, 320, caout, 257);
  k_g128r<false, true, false, 1, false><<<dim3(256), blk, 0, stream>>>(
      caout, 1024, wt_caproj, 1024, caproj_b, xres, nullptr, nullptr, xres, nullptr,
      4096, 1024, 1024, 8);

  // 5. ln3(xres) ; fc+gelu ; mproj -> hbf
  k_ln<<<dim3(4096), blk, 0, stream>>>(xres, ln3_g, ln3_b, lnout);
  k_g128r<true, false, true, 0, false><<<dim3(1024), blk, 0, stream>>>(
      lnout, 1024, wt_fc, 1024, fc_b, nullptr, nullptr, nullptr, nullptr, fcout,
      4096, 4096, 1024, 32);
  k_g128r<false, false, true, 0, false><<<dim3(256), blk, 0, stream>>>(
      fcout, 4096, wt_mproj, 4096, mproj_b, nullptr, nullptr, nullptr, nullptr, hbf,
      4096, 1024, 4096, 8);

  // 6. adapter: down+gelu ; up + up_b + h(bf16) + xres -> out
  k_g128r<true, false, true, 0, false><<<dim3(64), blk, 0, stream>>>(
      hbf, 1024, wt_down, 1024, down_b, nullptr, nullptr, nullptr, nullptr, dmid,
      4096, 256, 1024, 2);
  k_g128r<false, true, false, 2, true><<<dim3(256), blk, 0, stream>>>(
      dmid, 256, wt_up, 256, up_b, nullptr, hbf, xres, out, nullptr,
      4096, 1024, 256, 8);
}